// Round 5
// baseline (342.741 us; speedup 1.0000x reference)
//
#include <hip/hip_runtime.h>
#include <hip/hip_bf16.h>
#include <stdint.h>

// Problem constants
#define B_ROWS 16384
#define F_DIM  512
#define K_OUT  1000
#define K_PAD  1024

// GEMM tile (128x128, BK=64, 4 waves, ~65KB LDS -> 2 blocks/CU resident)
#define BM 128
#define BN 128
#define BK 64

typedef __attribute__((ext_vector_type(4))) float f32x4;
typedef __attribute__((ext_vector_type(8))) short short8;
typedef unsigned short u16;
typedef unsigned int   u32;

// packed f32x2 -> bf16x2 (RNE), D[15:0]=bf16(lo), D[31:16]=bf16(hi)
__device__ __forceinline__ u32 pkbf(float lo, float hi) {
  u32 d;
  asm("v_cvt_pk_bf16_f32 %0, %1, %2" : "=v"(d) : "v"(lo), "v"(hi));
  return d;
}

// ---- fully fused kernel: fp32 load -> bf16 LDS staging -> MFMA -> epilogue ----
// out[m][n] = gamma[n] * (2*cross[m][n] - dsq[m] - wsq[n]), n < K_OUT
//
// LDS tile: [128 rows][64 cols] bf16 (16KB each A,B; double-buffered = 64KB).
// Row = 128B = 8 slots of 16B; data for k-slot s stored at LDS slot (s ^ (row&7)).
// Reg-staging writes directly to the swizzled slot; global reads stay linear:
// thread (rs=tid>>3, s8=tid&7) loads 8 consecutive fp32 of row (band*32+rs)
// -> 8 lanes x 32B = 256B contiguous segments per row-group (coalesced).
//
// Per K-tile schedule (T14 split, one barrier per tile, no vmcnt(0) drains):
//   issue 16 fp32 loads for tile t+1            (VMEM in flight over compute)
//   ds_read 16 frags of tile t; 32 MFMA         (compiler inserts counted lgkm)
//   cvt+norm-fma+8 ds_write_b128 to next buf    (compiler inserts counted vmcnt)
//   s_waitcnt lgkmcnt(0); s_barrier             (LDS ops drained; VMEM untouched)
//
// dsq/wsq computed during staging from the fp32 data (8 fma/band), reduced
// across the 8 slot-lanes via shfl_xor into LDS -> no prep kernels at all.

#define LOAD_T(kb)                                                             \
  _Pragma("unroll") for (int p = 0; p < 4; ++p) {                              \
    const float* pA = Dg + (size_t)(p * 32 + rs) * F_DIM + (kb) + s8 * 8;      \
    la[p][0] = *(const float4*)pA;                                             \
    la[p][1] = *(const float4*)(pA + 4);                                       \
    int wr = n0 + p * 32 + rs;                                                 \
    if (wr < K_OUT) {                                                          \
      const float* pB = W + (size_t)wr * F_DIM + (kb) + s8 * 8;                \
      lb[p][0] = *(const float4*)pB;                                           \
      lb[p][1] = *(const float4*)(pB + 4);                                     \
    } else {                                                                   \
      lb[p][0] = make_float4(0.f, 0.f, 0.f, 0.f);                              \
      lb[p][1] = make_float4(0.f, 0.f, 0.f, 0.f);                              \
    }                                                                          \
  }

#define WRITE_T(dstA, dstB)                                                    \
  _Pragma("unroll") for (int p = 0; p < 4; ++p) {                              \
    int r = p * 32 + rs;                                                       \
    int so = ((s8 ^ (r & 7)) << 4);                                            \
    float4 u0 = la[p][0], u1 = la[p][1];                                       \
    pa[p] += u0.x*u0.x + u0.y*u0.y + u0.z*u0.z + u0.w*u0.w                     \
           + u1.x*u1.x + u1.y*u1.y + u1.z*u1.z + u1.w*u1.w;                    \
    uint4 qa;                                                                  \
    qa.x = pkbf(u0.x, u0.y); qa.y = pkbf(u0.z, u0.w);                          \
    qa.z = pkbf(u1.x, u1.y); qa.w = pkbf(u1.z, u1.w);                          \
    *(uint4*)((dstA) + r * 128 + so) = qa;                                     \
    float4 v0 = lb[p][0], v1 = lb[p][1];                                       \
    pw[p] += v0.x*v0.x + v0.y*v0.y + v0.z*v0.z + v0.w*v0.w                     \
           + v1.x*v1.x + v1.y*v1.y + v1.z*v1.z + v1.w*v1.w;                    \
    uint4 qb;                                                                  \
    qb.x = pkbf(v0.x, v0.y); qb.y = pkbf(v0.z, v0.w);                          \
    qb.z = pkbf(v1.x, v1.y); qb.w = pkbf(v1.z, v1.w);                          \
    *(uint4*)((dstB) + r * 128 + so) = qb;                                     \
  }

__global__ __launch_bounds__(256, 2) void gemm_eps(
    const float* __restrict__ D,     // [B_ROWS][F_DIM] fp32
    const float* __restrict__ W,     // [K_OUT][F_DIM]  fp32
    const float* __restrict__ gamma, // [K_OUT]
    float* __restrict__ out) {       // [B_ROWS][K_OUT]
  __shared__ __align__(16) char lds[66560];   // 2x(A 16KB + B 16KB) + norms 1KB
  float* dsq_s = (float*)(lds + 65536);        // [128]
  float* wsq_s = (float*)(lds + 65536 + 512);  // [128]

  const int tid  = threadIdx.x;
  const int w    = tid >> 6;     // wave 0..3
  const int lane = tid & 63;
  const int lr   = lane & 15;
  const int lk4  = lane >> 4;
  const int wm   = w >> 1;       // 2 M-waves
  const int wn   = w & 1;        // 2 N-waves
  const int rs   = tid >> 3;     // staging row within 32-row band (0..31)
  const int s8   = tid & 7;      // staging 8-float slot

  // XCD-aware swizzle (grid=1024, %8==0 -> bijective); consecutive wg on one
  // XCD share the A-panel -> A re-reads are local-L2 hits; all of W (2MB fp32)
  // is L2-resident per XCD.
  const int bid = blockIdx.x;
  const int wg  = (bid & 7) * 128 + (bid >> 3);
  const int mt  = wg >> 3;       // 128 M-tiles
  const int nt  = wg & 7;        // 8 N-tiles
  const int m0  = mt * BM;
  const int n0  = nt * BN;

  const float* Dg = D + (size_t)m0 * F_DIM;

  f32x4 acc[4][4];
#pragma unroll
  for (int i = 0; i < 4; ++i)
#pragma unroll
    for (int j = 0; j < 4; ++j) acc[i][j] = (f32x4){0.f, 0.f, 0.f, 0.f};
  float pa[4] = {0.f, 0.f, 0.f, 0.f};
  float pw[4] = {0.f, 0.f, 0.f, 0.f};

  // prologue: stage K-tile 0 into buf0
  {
    float4 la[4][2], lb[4][2];
    LOAD_T(0)
    WRITE_T(lds, lds + 16384)
    asm volatile("s_waitcnt lgkmcnt(0)" ::: "memory");
    __builtin_amdgcn_s_barrier();
  }

#pragma unroll
  for (int t = 0; t < 8; ++t) {
    char* sAc = lds + (t & 1) * 32768;
    char* sBc = sAc + 16384;
    char* sAn = lds + ((t + 1) & 1) * 32768;
    char* sBn = sAn + 16384;

    // issue next-tile fp32 loads early (latency hidden under frag-reads+MFMA)
    float4 la[4][2], lb[4][2];
    if (t < 7) { LOAD_T((t + 1) * BK) }

    // fragment reads of current tile
    short8 a[4][2], b[4][2];
#pragma unroll
    for (int mi = 0; mi < 4; ++mi)
#pragma unroll
      for (int kk = 0; kk < 2; ++kk) {
        int r  = wm * 64 + mi * 16 + lr;
        a[mi][kk] = *(const short8*)(sAc + r * 128 +
                                     ((((kk << 2) + lk4) ^ (r & 7)) << 4));
        int rn = wn * 64 + mi * 16 + lr;
        b[mi][kk] = *(const short8*)(sBc + rn * 128 +
                                     ((((kk << 2) + lk4) ^ (rn & 7)) << 4));
      }

    __builtin_amdgcn_s_setprio(1);
#pragma unroll
    for (int mi = 0; mi < 4; ++mi)
#pragma unroll
      for (int ni = 0; ni < 4; ++ni)
#pragma unroll
        for (int kk = 0; kk < 2; ++kk)
          acc[mi][ni] = __builtin_amdgcn_mfma_f32_16x16x32_bf16(
              a[mi][kk], b[ni][kk], acc[mi][ni], 0, 0, 0);
    __builtin_amdgcn_s_setprio(0);

    // convert + norm-accumulate + publish next tile
    if (t < 7) { WRITE_T(sAn, sBn) }
    asm volatile("s_waitcnt lgkmcnt(0)" ::: "memory");
    __builtin_amdgcn_s_barrier();
  }

  // ---- norm reduction across the 8 slot-lanes -> LDS ----
#pragma unroll
  for (int p = 0; p < 4; ++p) {
    float s = pa[p];
    s += __shfl_xor(s, 1); s += __shfl_xor(s, 2); s += __shfl_xor(s, 4);
    if (s8 == 0) dsq_s[p * 32 + rs] = s;
    float q = pw[p];
    q += __shfl_xor(q, 1); q += __shfl_xor(q, 2); q += __shfl_xor(q, 4);
    if (s8 == 0) wsq_s[p * 32 + rs] = q;
  }
  __syncthreads();

  // ---- fused epilogue via LDS transpose (coalesced 128B row stores) ----
  float g_[4], wq_[4];
#pragma unroll
  for (int ni = 0; ni < 4; ++ni) {
    int lcol = wn * 64 + ni * 16 + lr;
    int col  = n0 + lcol;
    g_[ni]  = (col < K_OUT) ? gamma[col] : 0.f;
    wq_[ni] = wsq_s[lcol];
  }
  float* ch = (float*)lds;       // chunk buffer [64][132] f32 (pad 132 -> <=2-way
  const int rl = tid >> 3;       // bank aliasing on write, 16B-aligned rows)
  const int cb = (tid & 7) << 2;
#pragma unroll
  for (int c = 0; c < 2; ++c) {
    __syncthreads();   // previous chunk fully read; K-loop LDS quiesced
    if (wm == c) {
#pragma unroll
      for (int mi = 0; mi < 4; ++mi) {
        const int row_l = mi * 16 + lk4 * 4;
#pragma unroll
        for (int j = 0; j < 4; ++j) {
          float dq = dsq_s[c * 64 + row_l + j];
#pragma unroll
          for (int ni = 0; ni < 4; ++ni) {
            ch[(row_l + j) * 132 + wn * 64 + ni * 16 + lr] =
                g_[ni] * (2.f * acc[mi][ni][j] - dq - wq_[ni]);
          }
        }
      }
    }
    __syncthreads();   // chunk visible to all waves
#pragma unroll
    for (int half = 0; half < 2; ++half) {
#pragma unroll
      for (int s = 0; s < 4; ++s) {
        int row = half * 32 + rl;
        int col = cb + s * 32;
        if (n0 + col < K_OUT) {
          float4 v = *(const float4*)&ch[row * 132 + col];
          *(float4*)&out[(size_t)(m0 + c * 64 + row) * K_OUT + n0 + col] = v;
        }
      }
    }
  }
}

extern "C" void kernel_launch(void* const* d_in, const int* in_sizes, int n_in,
                              void* d_out, int out_size, void* d_ws, size_t ws_size,
                              hipStream_t stream) {
  const float* D     = (const float*)d_in[0];
  const float* W     = (const float*)d_in[1];
  const float* gamma = (const float*)d_in[2];
  float* out = (float*)d_out;

  // single fused dispatch: grid = (16384/128) * (1024/128) = 1024 blocks
  gemm_eps<<<(B_ROWS / BM) * (K_PAD / BN), 256, 0, stream>>>(D, W, gamma, out);
}

// Round 6
// 64.463 us; speedup vs baseline: 5.3169x; 5.3169x over previous
//
#include <hip/hip_runtime.h>
#include <hip/hip_bf16.h>
#include <stdint.h>

// Problem constants
#define B_ROWS 16384
#define F_DIM  512
#define K_OUT  1000
#define K_PAD  1024

// GEMM tile (128x128, BK=64, 4 waves, 64KB+ LDS -> 2 blocks/CU resident)
#define BM 128
#define BN 128
#define BK 64

typedef __attribute__((ext_vector_type(4))) float f32x4;
typedef __attribute__((ext_vector_type(8))) short short8;
typedef unsigned short u16;
typedef unsigned int   u32;

// Workspace layout (bytes)
#define OFF_WB   0                 // 1024*512*2 = 1048576
#define OFF_WSQ  1048576           // 1024*4     = 4096

__device__ __forceinline__ u16 f2bf(float f) {
  union { float f; u32 u; } v; v.f = f;
  u32 u = v.u;
  u32 r = (u + 0x7fffu + ((u >> 16) & 1u)) >> 16;   // RNE
  return (u16)r;
}

// packed f32x2 -> bf16x2 (RNE), D[15:0]=bf16(lo), D[31:16]=bf16(hi)
__device__ __forceinline__ u32 pkbf(float lo, float hi) {
  u32 d;
  asm("v_cvt_pk_bf16_f32 %0, %1, %2" : "=v"(d) : "v"(lo), "v"(hi));
  return d;
}

// ---- prep: cast W -> bf16 padded to K_PAD rows, row sums of squares ----
__global__ void prep_W(const float* __restrict__ W, u16* __restrict__ Wb,
                       float* __restrict__ wsq) {
  int w    = threadIdx.x >> 6;
  int lane = threadIdx.x & 63;
  int row  = blockIdx.x * 4 + w;
  uint4 p; p.x = p.y = p.z = p.w = 0u;
  float s = 0.f;
  if (row < K_OUT) {
    const float* src = W + (size_t)row * F_DIM + lane * 8;
    float4 v0 = *(const float4*)src;
    float4 v1 = *(const float4*)(src + 4);
    s = v0.x*v0.x + v0.y*v0.y + v0.z*v0.z + v0.w*v0.w
      + v1.x*v1.x + v1.y*v1.y + v1.z*v1.z + v1.w*v1.w;
    p.x = (u32)f2bf(v0.x) | ((u32)f2bf(v0.y) << 16);
    p.y = (u32)f2bf(v0.z) | ((u32)f2bf(v0.w) << 16);
    p.z = (u32)f2bf(v1.x) | ((u32)f2bf(v1.y) << 16);
    p.w = (u32)f2bf(v1.z) | ((u32)f2bf(v1.w) << 16);
  }
#pragma unroll
  for (int off = 32; off >= 1; off >>= 1) s += __shfl_xor(s, off);
  if (lane == 0) wsq[row] = s;
  *(uint4*)(Wb + (size_t)row * F_DIM + lane * 8) = p;
}

// ---- fused GEMM: A reg-staged from fp32 D (+dsq), B reg-staged from bf16 Wb ----
// out[m][n] = gamma[n] * (2*cross[m][n] - dsq[m] - wsq[n]), n < K_OUT
//
// LDS tile: [128 rows][64 cols] bf16 (16KB each A,B; double-buffered = 64KB).
// Row = 128B = 8 slots of 16B; k-slot s stored at LDS slot (s ^ (row&7)).
// Reg-staging writes the swizzled slot directly; global reads stay linear
// (thread rs=tid>>3, s8=tid&7 -> 8 lanes x 32B contiguous per A row; 16B for B).
//
// Per K-tile (ONE barrier, no hand vmcnt -- all waits compiler-counted):
//   issue 12 global loads for tile t+1 (8xA fp32, 4xB bf16)   [in flight]
//   2 x { 8 ds_read_b128 frags ; 16 MFMA }                    [hides lgkm+vmem]
//   cvt+dsq-fma+8 ds_write_b128 -> other buffer               [vmcnt by compiler]
//   s_waitcnt lgkmcnt(0); s_barrier                           [writes visible]
//
// Register budget (~180): acc 64 + frags 32 + A-inflight 32 + B-inflight 16.

#define LOAD_T(kb)                                                             \
  _Pragma("unroll") for (int p = 0; p < 4; ++p) {                              \
    const float* pA = Dg + (size_t)(p * 32 + rs) * F_DIM + (kb) + s8 * 8;      \
    la[p][0] = *(const float4*)pA;                                             \
    la[p][1] = *(const float4*)(pA + 4);                                       \
    lbq[p]   = *(const uint4*)(Wg + (size_t)(p * 32 + rs) * F_DIM + (kb) + s8 * 8); \
  }

#define WRITE_T(dstA, dstB)                                                    \
  _Pragma("unroll") for (int p = 0; p < 4; ++p) {                              \
    int r  = p * 32 + rs;                                                      \
    int so = ((s8 ^ (r & 7)) << 4);                                            \
    float4 u0 = la[p][0], u1 = la[p][1];                                       \
    pa[p] += u0.x*u0.x + u0.y*u0.y + u0.z*u0.z + u0.w*u0.w                     \
           + u1.x*u1.x + u1.y*u1.y + u1.z*u1.z + u1.w*u1.w;                    \
    uint4 qa;                                                                  \
    qa.x = pkbf(u0.x, u0.y); qa.y = pkbf(u0.z, u0.w);                          \
    qa.z = pkbf(u1.x, u1.y); qa.w = pkbf(u1.z, u1.w);                          \
    *(uint4*)((dstA) + r * 128 + so) = qa;                                     \
    *(uint4*)((dstB) + r * 128 + so) = lbq[p];                                 \
  }

__global__ __launch_bounds__(256, 2) void gemm_eps(
    const float* __restrict__ D,     // [B_ROWS][F_DIM] fp32
    const u16*   __restrict__ Wb,    // [K_PAD][F_DIM]  bf16 (padded rows 0)
    const float* __restrict__ wsq,   // [K_PAD]
    const float* __restrict__ gamma, // [K_OUT]
    float* __restrict__ out) {       // [B_ROWS][K_OUT]
  __shared__ __align__(16) char lds[66048];   // 2x(A 16KB + B 16KB) + dsq 512B
  float* dsq_s = (float*)(lds + 65536);        // [128]

  const int tid  = threadIdx.x;
  const int w    = tid >> 6;     // wave 0..3
  const int lane = tid & 63;
  const int lr   = lane & 15;
  const int lk4  = lane >> 4;
  const int wm   = w >> 1;       // 2 M-waves
  const int wn   = w & 1;        // 2 N-waves
  const int rs   = tid >> 3;     // staging row within 32-row band (0..31)
  const int s8   = tid & 7;      // staging 16B slot

  // XCD-aware swizzle (grid=1024, %8==0 -> bijective); the 8 consecutive wg on
  // one XCD share mt -> the A-panel (fp32) is fetched from HBM once per XCD.
  const int bid = blockIdx.x;
  const int wg  = (bid & 7) * 128 + (bid >> 3);
  const int mt  = wg >> 3;       // 128 M-tiles
  const int nt  = wg & 7;        // 8 N-tiles
  const int m0  = mt * BM;
  const int n0  = nt * BN;

  const float* Dg = D  + (size_t)m0 * F_DIM;
  const u16*   Wg = Wb + (size_t)n0 * F_DIM;

  f32x4 acc[4][4];
#pragma unroll
  for (int i = 0; i < 4; ++i)
#pragma unroll
    for (int j = 0; j < 4; ++j) acc[i][j] = (f32x4){0.f, 0.f, 0.f, 0.f};
  float pa[4] = {0.f, 0.f, 0.f, 0.f};

  // prologue: stage K-tile 0 into buf0
  {
    float4 la[4][2]; uint4 lbq[4];
    LOAD_T(0)
    WRITE_T(lds, lds + 16384)
    asm volatile("s_waitcnt lgkmcnt(0)" ::: "memory");
    __builtin_amdgcn_sched_barrier(0);
    __builtin_amdgcn_s_barrier();
  }

#pragma unroll 2
  for (int t = 0; t < 8; ++t) {
    char* sAc = lds + (t & 1) * 32768;
    char* sBc = sAc + 16384;
    char* sAn = lds + ((t + 1) & 1) * 32768;
    char* sBn = sAn + 16384;

    // issue next-tile loads early (latency hidden under frag reads + MFMA)
    float4 la[4][2]; uint4 lbq[4];
    if (t < 7) { LOAD_T((t + 1) * BK) }

#pragma unroll
    for (int kk = 0; kk < 2; ++kk) {
      short8 a[4], b[4];
#pragma unroll
      for (int mi = 0; mi < 4; ++mi) {
        int rA = wm * 64 + mi * 16 + lr;
        a[mi] = *(const short8*)(sAc + rA * 128 +
                                 ((((kk << 2) + lk4) ^ (rA & 7)) << 4));
        int rB = wn * 64 + mi * 16 + lr;
        b[mi] = *(const short8*)(sBc + rB * 128 +
                                 ((((kk << 2) + lk4) ^ (rB & 7)) << 4));
      }
      __builtin_amdgcn_s_setprio(1);
#pragma unroll
      for (int mi = 0; mi < 4; ++mi)
#pragma unroll
        for (int ni = 0; ni < 4; ++ni)
          acc[mi][ni] = __builtin_amdgcn_mfma_f32_16x16x32_bf16(
              a[mi], b[ni], acc[mi][ni], 0, 0, 0);
      __builtin_amdgcn_s_setprio(0);
    }

    // convert + dsq-accumulate + publish next tile into the other buffer
    if (t < 7) { WRITE_T(sAn, sBn) }
    asm volatile("s_waitcnt lgkmcnt(0)" ::: "memory");
    __builtin_amdgcn_sched_barrier(0);
    __builtin_amdgcn_s_barrier();
  }

  // ---- dsq reduction across the 8 slot-lanes -> LDS ----
#pragma unroll
  for (int p = 0; p < 4; ++p) {
    float s = pa[p];
    s += __shfl_xor(s, 1); s += __shfl_xor(s, 2); s += __shfl_xor(s, 4);
    if (s8 == 0) dsq_s[p * 32 + rs] = s;
  }
  __syncthreads();

  // ---- fused epilogue via LDS transpose (coalesced 128B row stores) ----
  float g_[4], wq_[4];
#pragma unroll
  for (int ni = 0; ni < 4; ++ni) {
    int col = n0 + wn * 64 + ni * 16 + lr;
    g_[ni]  = (col < K_OUT) ? gamma[col] : 0.f;
    wq_[ni] = wsq[col & (K_PAD - 1)];
  }
  float* ch = (float*)lds;       // chunk buffer [64][132] f32 (pad 132 -> <=2-way
  const int rl = tid >> 3;       // bank aliasing on write, 16B-aligned rows)
  const int cb = (tid & 7) << 2;
#pragma unroll
  for (int c = 0; c < 2; ++c) {
    __syncthreads();   // previous chunk fully read; K-loop LDS quiesced
    if (wm == c) {
#pragma unroll
      for (int mi = 0; mi < 4; ++mi) {
        const int row_l = mi * 16 + lk4 * 4;
#pragma unroll
        for (int j = 0; j < 4; ++j) {
          float dq = dsq_s[c * 64 + row_l + j];
#pragma unroll
          for (int ni = 0; ni < 4; ++ni) {
            ch[(row_l + j) * 132 + wn * 64 + ni * 16 + lr] =
                g_[ni] * (2.f * acc[mi][ni][j] - dq - wq_[ni]);
          }
        }
      }
    }
    __syncthreads();   // chunk visible to all waves
#pragma unroll
    for (int half = 0; half < 2; ++half) {
#pragma unroll
      for (int s = 0; s < 4; ++s) {
        int row = half * 32 + rl;
        int col = cb + s * 32;
        if (n0 + col < K_OUT) {
          float4 v = *(const float4*)&ch[row * 132 + col];
          *(float4*)&out[(size_t)(m0 + c * 64 + row) * K_OUT + n0 + col] = v;
        }
      }
    }
  }
}

extern "C" void kernel_launch(void* const* d_in, const int* in_sizes, int n_in,
                              void* d_out, int out_size, void* d_ws, size_t ws_size,
                              hipStream_t stream) {
  const float* D     = (const float*)d_in[0];
  const float* W     = (const float*)d_in[1];
  const float* gamma = (const float*)d_in[2];
  float* out = (float*)d_out;
  char*  ws  = (char*)d_ws;

  u16*   Wb  = (u16*)(ws + OFF_WB);
  float* wsq = (float*)(ws + OFF_WSQ);

  prep_W<<<K_PAD / 4, 256, 0, stream>>>(W, Wb, wsq);

  // grid = (16384/128) * (1024/128) = 1024 blocks, 2 resident/CU
  gemm_eps<<<(B_ROWS / BM) * (K_PAD / BN), 256, 0, stream>>>(
      D, Wb, wsq, gamma, out);
}

// Round 7
// 39.731 us; speedup vs baseline: 8.6266x; 1.6225x over previous
//
#include <hip/hip_runtime.h>
#include <hip/hip_bf16.h>
#include <stdint.h>

// Problem constants
#define B_ROWS 16384
#define F_DIM  512
#define K_OUT  1000
#define K_PAD  1024

// GEMM tile (128x128, BK=64, 4 waves, 64KB LDS -> 2 blocks/CU resident)
#define BM 128
#define BN 128
#define BK 64

typedef __attribute__((ext_vector_type(4))) float f32x4;
typedef __attribute__((ext_vector_type(8))) short short8;
typedef unsigned short u16;
typedef unsigned int   u32;

// Workspace layout (bytes)
#define OFF_DB   0                               // 16384*512*2 = 16777216
#define OFF_WB   16777216                        // 1024*512*2  = 1048576
#define OFF_DSQ  (16777216 + 1048576)            // 16384*4     = 65536
#define OFF_WSQ  (16777216 + 1048576 + 65536)    // 1024*4      = 4096

__device__ __forceinline__ u16 f2bf(float f) {
  union { float f; u32 u; } v; v.f = f;
  u32 u = v.u;
  u32 r = (u + 0x7fffu + ((u >> 16) & 1u)) >> 16;   // RNE
  return (u16)r;
}

// ---- merged prep: cast D,W -> bf16 (+pad W), row sums of squares ----
__global__ void prep(const float* __restrict__ D, const float* __restrict__ W,
                     u16* __restrict__ Db, u16* __restrict__ Wb,
                     float* __restrict__ dsq, float* __restrict__ wsq) {
  int w    = threadIdx.x >> 6;
  int lane = threadIdx.x & 63;
  if (blockIdx.x < B_ROWS / 4) {
    int row = blockIdx.x * 4 + w;
    const float* src = D + (size_t)row * F_DIM + lane * 8;
    float4 v0 = *(const float4*)src;
    float4 v1 = *(const float4*)(src + 4);
    float s = v0.x*v0.x + v0.y*v0.y + v0.z*v0.z + v0.w*v0.w
            + v1.x*v1.x + v1.y*v1.y + v1.z*v1.z + v1.w*v1.w;
#pragma unroll
    for (int off = 32; off >= 1; off >>= 1) s += __shfl_xor(s, off);
    if (lane == 0) dsq[row] = s;
    uint4 p;
    p.x = (u32)f2bf(v0.x) | ((u32)f2bf(v0.y) << 16);
    p.y = (u32)f2bf(v0.z) | ((u32)f2bf(v0.w) << 16);
    p.z = (u32)f2bf(v1.x) | ((u32)f2bf(v1.y) << 16);
    p.w = (u32)f2bf(v1.z) | ((u32)f2bf(v1.w) << 16);
    *(uint4*)(Db + (size_t)row * F_DIM + lane * 8) = p;
  } else {
    int row = (blockIdx.x - B_ROWS / 4) * 4 + w;
    uint4 p; p.x = p.y = p.z = p.w = 0u;
    float s = 0.f;
    if (row < K_OUT) {
      const float* src = W + (size_t)row * F_DIM + lane * 8;
      float4 v0 = *(const float4*)src;
      float4 v1 = *(const float4*)(src + 4);
      s = v0.x*v0.x + v0.y*v0.y + v0.z*v0.z + v0.w*v0.w
        + v1.x*v1.x + v1.y*v1.y + v1.z*v1.z + v1.w*v1.w;
      p.x = (u32)f2bf(v0.x) | ((u32)f2bf(v0.y) << 16);
      p.y = (u32)f2bf(v0.z) | ((u32)f2bf(v0.w) << 16);
      p.z = (u32)f2bf(v1.x) | ((u32)f2bf(v1.y) << 16);
      p.w = (u32)f2bf(v1.z) | ((u32)f2bf(v1.w) << 16);
    }
#pragma unroll
    for (int off = 32; off >= 1; off >>= 1) s += __shfl_xor(s, off);
    if (lane == 0) wsq[row] = s;
    *(uint4*)(Wb + (size_t)row * F_DIM + lane * 8) = p;
  }
}

// ---- async global -> LDS, 16B per lane (dest is wave-uniform base + lane*16) ----
__device__ __forceinline__ void gload_lds16(const void* g, void* l) {
  __builtin_amdgcn_global_load_lds(
      (const __attribute__((address_space(1))) void*)g,
      (__attribute__((address_space(3))) void*)l,
      16, 0, 0);
}

// ---- main GEMM + fused epilogue: 128x128 tile, 4 waves, 1 phase per K-tile ----
// out[m][n] = gamma[n] * (2*cross[m][n] - dsq[m] - wsq[n]), n < K_OUT
//
// LDS tile: [128 rows][64 cols] bf16 (16KB each A,B; double-buffered = 64KB).
// Row = 128B = 8 slots of 16B; k-slot s stored at LDS slot (s ^ (row&7)) via
// pre-swizzled global source (both-sides involution, rule #21).
//
// Per K-tile (2 barriers, uniform counted vmcnt, no vmcnt(0) in loop):
//   issue 8 gload_lds for tile t+1 into buf[(t+1)&1]   (phantom wrap at t=7)
//   s_waitcnt vmcnt(8)  -> exactly tile t's 8 loads have landed
//   s_barrier           -> all waves' tile-t data resident
//   16 ds_read_b128 frags; setprio(1); 32 MFMA; setprio(0)
//   s_barrier           -> buf[t&1] reads done before t+1 stages over it
// 16 barriers/block vs round-4's 64 -- the barrier-bound hypothesis test.

#define STAGE_A(h)                                                             \
  _Pragma("unroll") for (int j = 0; j < 2; ++j) {                              \
    int rb = (h) * 32 + j * 64 + w * 8;                                        \
    int r  = rb + (lane >> 3);                                                 \
    int sc = s8 ^ (r & 7);                                                     \
    gload_lds16(Ag + (size_t)r * F_DIM + kbn + sc * 8, sAn + rb * 128);        \
  }

#define STAGE_B(q)                                                             \
  _Pragma("unroll") for (int j = 0; j < 2; ++j) {                              \
    int rb = (q) * 32 + j * 64 + w * 8;                                        \
    int r  = rb + (lane >> 3);                                                 \
    int sc = s8 ^ (r & 7);                                                     \
    gload_lds16(Bg + (size_t)r * F_DIM + kbn + sc * 8, sBn + rb * 128);        \
  }

__global__ __launch_bounds__(256, 2) void gemm_eps(
    const u16* __restrict__ A,   // [B_ROWS][F_DIM] bf16
    const u16* __restrict__ Bw,  // [K_PAD][F_DIM]  bf16 (padded rows are 0)
    const float* __restrict__ dsq,
    const float* __restrict__ wsq,
    const float* __restrict__ gamma,
    float* __restrict__ out) {
  __shared__ __align__(16) char lds[65536];   // 2 x (A 16KB + B 16KB)

  const int tid  = threadIdx.x;
  const int w    = tid >> 6;     // wave 0..3
  const int lane = tid & 63;
  const int lr   = lane & 15;
  const int lk4  = lane >> 4;
  const int wm   = w >> 1;       // 2 M-waves
  const int wn   = w & 1;        // 2 N-waves

  // XCD-aware swizzle (grid=1024, %8==0 -> bijective). Consecutive wg on one
  // XCD share the A-panel (same mt) -> A re-reads are local-L2 hits.
  const int bid = blockIdx.x;
  const int wg  = (bid & 7) * 128 + (bid >> 3);
  const int mt  = wg >> 3;       // 128 M-tiles
  const int nt  = wg & 7;        // 8 N-tiles
  const int m0  = mt * BM;
  const int n0  = nt * BN;

  const u16* Ag = A  + (size_t)m0 * F_DIM;
  const u16* Bg = Bw + (size_t)n0 * F_DIM;

  const int s8 = lane & 7;       // staging 16B slot

  f32x4 acc[4][4];
#pragma unroll
  for (int i = 0; i < 4; ++i)
#pragma unroll
    for (int j = 0; j < 4; ++j) acc[i][j] = (f32x4){0.f, 0.f, 0.f, 0.f};

  // prefetch ALL epilogue operands into registers before the K-loop: the
  // epilogue becomes pure LDS+stores, and these loads hide under the K-loop.
  float g_[4], wq_[4];
  float4 dl[4];
#pragma unroll
  for (int ni = 0; ni < 4; ++ni) {
    int col = n0 + wn * 64 + ni * 16 + lr;
    g_[ni]  = (col < K_OUT) ? gamma[col] : 0.f;
    wq_[ni] = wsq[col & (K_PAD - 1)];
  }
#pragma unroll
  for (int mi = 0; mi < 4; ++mi)
    dl[mi] = *(const float4*)&dsq[m0 + wm * 64 + mi * 16 + lk4 * 4];

  // prologue: stage K-tile 0 into buf0 (8 loads/thread, in flight)
  {
    char* sAn = lds;
    char* sBn = lds + 16384;
    const int kbn = 0;
    STAGE_A(0) STAGE_A(1) STAGE_B(0) STAGE_B(1)
  }

#pragma unroll 2
  for (int t = 0; t < 8; ++t) {
    char* sAc = lds + (t & 1) * 32768;
    char* sBc = sAc + 16384;
    char* sAn = lds + ((t + 1) & 1) * 32768;
    char* sBn = sAn + 16384;
    const int kbn = ((t + 1) & 7) * BK;  // t=7 phantom wraps to k=0: harmless

    // issue next tile's 8 loads (kept in flight across this tile's compute)
    STAGE_A(0) STAGE_A(1) STAGE_B(0) STAGE_B(1)

    asm volatile("s_waitcnt vmcnt(8)" ::: "memory");  // tile t resident
    __builtin_amdgcn_s_barrier();
    asm volatile("" ::: "memory");

    short8 a[2][4], b[2][4];
#pragma unroll
    for (int kk = 0; kk < 2; ++kk)
#pragma unroll
      for (int mi = 0; mi < 4; ++mi) {
        int rA = wm * 64 + mi * 16 + lr;
        a[kk][mi] = *(const short8*)(sAc + rA * 128 +
                                     ((((kk << 2) + lk4) ^ (rA & 7)) << 4));
        int rB = wn * 64 + mi * 16 + lr;
        b[kk][mi] = *(const short8*)(sBc + rB * 128 +
                                     ((((kk << 2) + lk4) ^ (rB & 7)) << 4));
      }

    __builtin_amdgcn_s_setprio(1);
#pragma unroll
    for (int kk = 0; kk < 2; ++kk)
#pragma unroll
      for (int mi = 0; mi < 4; ++mi)
#pragma unroll
        for (int ni = 0; ni < 4; ++ni)
          acc[mi][ni] = __builtin_amdgcn_mfma_f32_16x16x32_bf16(
              a[kk][mi], b[kk][ni], acc[mi][ni], 0, 0, 0);
    __builtin_amdgcn_s_setprio(0);

    asm volatile("" ::: "memory");
    __builtin_amdgcn_s_barrier();   // buf[t&1] reads done before t+1 overwrites
  }

  // ---- fused epilogue via LDS transpose (coalesced 128B row stores) ----
  // First __syncthreads drains vmcnt(0)+lgkmcnt(0): the phantom tile-8 stages
  // land in buf0 before we overwrite LDS with the chunk buffer.
  float* ch = (float*)lds;       // chunk buffer [64][132] f32 (pad 132 -> <=2-way
  const int rl = tid >> 3;       // bank aliasing on write, 16B-aligned rows)
  const int cb = (tid & 7) << 2;
#pragma unroll
  for (int c = 0; c < 2; ++c) {
    __syncthreads();   // previous chunk fully read; K-loop LDS quiesced
    if (wm == c) {
#pragma unroll
      for (int mi = 0; mi < 4; ++mi) {
        const int row_l = mi * 16 + lk4 * 4;
#pragma unroll
        for (int j = 0; j < 4; ++j) {
          float dq = (j == 0) ? dl[mi].x : (j == 1) ? dl[mi].y
                   : (j == 2) ? dl[mi].z : dl[mi].w;
#pragma unroll
          for (int ni = 0; ni < 4; ++ni) {
            ch[(row_l + j) * 132 + wn * 64 + ni * 16 + lr] =
                g_[ni] * (2.f * acc[mi][ni][j] - dq - wq_[ni]);
          }
        }
      }
    }
    __syncthreads();   // chunk visible to all waves
#pragma unroll
    for (int half = 0; half < 2; ++half) {
#pragma unroll
      for (int s = 0; s < 4; ++s) {
        int row = half * 32 + rl;
        int col = cb + s * 32;
        if (n0 + col < K_OUT) {
          float4 v = *(const float4*)&ch[row * 132 + col];
          *(float4*)&out[(size_t)(m0 + c * 64 + row) * K_OUT + n0 + col] = v;
        }
      }
    }
  }
}

extern "C" void kernel_launch(void* const* d_in, const int* in_sizes, int n_in,
                              void* d_out, int out_size, void* d_ws, size_t ws_size,
                              hipStream_t stream) {
  const float* D     = (const float*)d_in[0];
  const float* W     = (const float*)d_in[1];
  const float* gamma = (const float*)d_in[2];
  float* out = (float*)d_out;
  char*  ws  = (char*)d_ws;

  u16*   Db  = (u16*)(ws + OFF_DB);
  u16*   Wb  = (u16*)(ws + OFF_WB);
  float* dsq = (float*)(ws + OFF_DSQ);
  float* wsq = (float*)(ws + OFF_WSQ);

  prep<<<B_ROWS / 4 + K_PAD / 4, 256, 0, stream>>>(D, W, Db, Wb, dsq, wsq);

  // grid = (16384/128) * (1024/128) = 1024 blocks, 2 resident/CU
  gemm_eps<<<(B_ROWS / BM) * (K_PAD / BN), 256, 0, stream>>>(
      Db, Wb, dsq, wsq, gamma, out);
}